// Round 15
// baseline (195.524 us; speedup 1.0000x reference)
//
#include <hip/hip_runtime.h>
#include <hip/hip_bf16.h>
#include <math.h>

typedef unsigned short ushort;
typedef __attribute__((ext_vector_type(8))) short bf16x8;
typedef __attribute__((ext_vector_type(4))) float f32x4;
typedef __attribute__((ext_vector_type(8))) ushort ushort8;

__device__ inline ushort f2bf(float f) {
  __hip_bfloat16 h = __float2bfloat16(f);
  return *reinterpret_cast<ushort*>(&h);
}

typedef __attribute__((address_space(3))) unsigned int lds_u32;
typedef __attribute__((address_space(1))) const unsigned int glb_u32;
__device__ __forceinline__ void gl2lds16(const ushort* g, ushort* l) {
  __builtin_amdgcn_global_load_lds((glb_u32*)g, (lds_u32*)l, 16, 0, 0);
}

#define S_BARRIER asm volatile("s_barrier" ::: "memory")
#define WAITV0 asm volatile("s_waitcnt vmcnt(0)" ::: "memory")

// soft grid barrier: all 256 blocks co-resident (1 block/CU). Device-scope
// arrival + acquire spin; counters zeroed by pack_all each call (replay-safe).
__device__ __forceinline__ void grid_bar(unsigned* cnt, int tid) {
  __threadfence();
  __syncthreads();
  if (tid == 0) {
    atomicAdd(cnt, 1u);
    while (__hip_atomic_load(cnt, __ATOMIC_ACQUIRE,
                             __HIP_MEMORY_SCOPE_AGENT) < 256u) {
      __builtin_amdgcn_s_sleep(1);
    }
  }
  __syncthreads();
  __threadfence();
}

// ============================ pack_all =====================================
// X-MAJOR world: spatial transpose. xn_pad[b][66 Xp][66 Yp][64 c].
// Weights tap-transposed: wp[t'] = w_orig[ky = t'%3][kx = t'/3].
// Last block zeroes pooled(256) + stats(128) + barrier counters(32).
__global__ __launch_bounds__(256) void pack_all(
    const float* __restrict__ x, const float* __restrict__ w1,
    const float* __restrict__ w2, ushort* __restrict__ xn_pad,
    ushort* __restrict__ w1p, ushort* __restrict__ w2p,
    ushort* __restrict__ h1n_pad, float* __restrict__ zbase) {
  int blk = blockIdx.x;
  int tid = threadIdx.x;
  __shared__ float ld[64][65];
  if (blk < 264) {
    int b = blk / 66, yp = blk % 66;
    if (yp == 0 || yp == 65) {
      for (int i = tid; i < 66 * 64; i += 256) {
        int xp = i >> 6, c = i & 63;
        xn_pad[((size_t)(b * 66 + xp)) * 4224 + yp * 64 + c] = 0;
      }
      return;
    }
    int y = yp - 1;
    int xx = tid & 63;
#pragma unroll
    for (int i = 0; i < 16; ++i) {
      int c = i * 4 + (tid >> 6);
      ld[c][xx] = x[((b * 64 + c) * 64 + y) * 64 + xx];
    }
    __syncthreads();
    for (int i = tid; i < 2 * 64; i += 256) {
      int side = i >> 6, c = i & 63;
      xn_pad[((size_t)(b * 66 + (side ? 65 : 0))) * 4224 + yp * 64 + c] = 0;
    }
    for (int u = tid; u < 64 * 8; u += 256) {
      int xp = u >> 3, cg = u & 7;
      ushort8 v;
#pragma unroll
      for (int j = 0; j < 8; ++j) v[j] = f2bf(ld[cg * 8 + j][xp]);
      *reinterpret_cast<ushort8*>(
          &xn_pad[((size_t)(b * 66 + xp + 1)) * 4224 + yp * 64 + cg * 8]) = v;
    }
  } else if (blk < 328) {
    int idx = (blk - 264) * 256 + tid;  // OC=256, CIN=64
    float v[9];
#pragma unroll
    for (int t = 0; t < 9; ++t) v[t] = w1[idx * 9 + t];
    int oc = idx >> 6, c = idx & 63;
#pragma unroll
    for (int tp = 0; tp < 9; ++tp)
      w1p[(tp * 256 + oc) * 64 + c] = f2bf(v[(tp % 3) * 3 + tp / 3]);
  } else if (blk < 1352) {
    int idx = (blk - 328) * 256 + tid;  // OC=1024, CIN=256
    float v[9];
#pragma unroll
    for (int t = 0; t < 9; ++t) v[t] = w2[(size_t)idx * 9 + t];
    int oc = idx >> 8, c = idx & 255;
#pragma unroll
    for (int tp = 0; tp < 9; ++tp)
      w2p[((size_t)tp * 1024 + oc) * 256 + c] = f2bf(v[(tp % 3) * 3 + tp / 3]);
  } else if (blk < 2392) {
    int k = blk - 1352;  // 0..1039
    int b = k / 260, p = k % 260;
    int yp, xp;
    if (p < 66) { yp = 0; xp = p; }
    else if (p < 132) { yp = 65; xp = p - 66; }
    else if (p < 196) { yp = p - 132 + 1; xp = 0; }
    else { yp = p - 196 + 1; xp = 65; }
    h1n_pad[((size_t)(b * 66 + xp) * 66 + yp) * 256 + tid] = 0;
  } else {
    if (tid < 104) {
      float4 z = {0.f, 0.f, 0.f, 0.f};
      *reinterpret_cast<float4*>(zbase + tid * 4) = z;
    }
  }
}

// ========== 2-block/CU pipelined implicit-GEMM conv (3x3, pad 1) ============
// R8-proven structure (77.7us, MfmaUtil 41%, 0 bank conflicts), 16x16x32 MFMA.
// Six schedule variants all converge to 78+-6us -> structural floor (mixed
// LDS-read-throughput + VALU bound); conv2 left at proven configuration.
// X-major. in_pad: [b][66 X][66 Y][CIN] bf16. wpack: [9][NOC][CIN].
// BM=128 (2 X-cols x 64 Y), BN=128, 4 waves (2M x 2N), wave tile 64x64.
// LDS = A 33792 + 2 x 16384 B = 66560 -> 2 blocks/CU.
template<int C1B, int NOC, int MODE>
__global__ __launch_bounds__(256, 2) void conv_gemm3(
    const ushort* __restrict__ in_pad, const ushort* __restrict__ wpack,
    const float* __restrict__ bias, ushort* __restrict__ outp,
    float* __restrict__ U, float* __restrict__ h0raw,
    float* __restrict__ h63raw) {
  constexpr int CIN = C1B * 64;
  constexpr int NSTEP = C1B * 9;
  constexpr int BN = 128;
  constexpr int BUFU = BN * 64;      // 8192 ushorts per B buffer
  constexpr int ACH = 4 * 66 * 8;    // 2112 A chunks (4 X-rows x 66 Y x 8)
  extern __shared__ ushort lds[];
  ushort* Araw = lds;                // 33792 B
  ushort* Bb = lds + ACH * 8;        // 2 x 16384 B
  int tid = threadIdx.x;
  int wid = tid >> 6, lane = tid & 63;
  int lrow = lane & 15, lk = lane >> 4;
  int wm = wid >> 1, wn = wid & 1;
  int bx = blockIdx.x, by = blockIdx.y;
  if constexpr (MODE == 1) {         // XCD swizzle: each XCD owns one B panel
    int id = bx + 128 * by;          // grid (128, 8), 1024 blocks
    int swz = (id & 7) * 128 + (id >> 3);
    bx = swz & 127;
    by = swz >> 7;
  }
  int P0 = bx * 128;
  int b = P0 >> 12;
  int x0 = (P0 & 4095) >> 6;         // X-pair origin
  int ocB = by * BN;
  f32x4 acc[4][4] = {};

  // precomputed per-thread staging offsets
  int aoff[9];
#pragma unroll
  for (int it = 0; it < 9; ++it) {
    int ch = it * 256 + tid;
    int slot = ch >> 3, cg = ch & 7;
    int xs = slot % 66;
    int cgp = cg ^ (xs & 7);
    aoff[it] = slot * CIN + cgp * 8;
  }
  int boff[4];
#pragma unroll
  for (int it = 0; it < 4; ++it) {
    int ch = it * 256 + tid;
    int oc = ch >> 3, cg = ch & 7;
    int cgp = cg ^ (oc & 7);
    boff[it] = oc * CIN + cgp * 8;
  }

  auto stageA = [&](int cb) {
    const ushort* asrc = in_pad + (size_t)(b * 66 + x0) * 66 * CIN + cb * 64;
#pragma unroll
    for (int it = 0; it < 9; ++it) {
      int basech = it * 256 + wid * 64;
      if (basech < ACH)
        gl2lds16(asrc + aoff[it], Araw + basech * 8);
    }
  };
  auto stageB = [&](int sstep, int q) {
    const ushort* wsrc =
        wpack + ((size_t)(sstep % 9) * NOC + ocB) * CIN + (sstep / 9) * 64;
    ushort* dbase = Bb + q * BUFU;
#pragma unroll
    for (int it = 0; it < 4; ++it)
      gl2lds16(wsrc + boff[it], dbase + (it * 256 + wid * 64) * 8);
  };

  // prologue
  stageA(0);
  stageB(0, 0);
  WAITV0;
  S_BARRIER;

#pragma unroll 1
  for (int cb = 0; cb < C1B; ++cb) {
#pragma unroll 1
    for (int t = 0; t < 9; ++t) {
      int step = cb * 9 + t;
      int ky = t / 3, kx = t - ky * 3;
      const ushort* bcur = Bb + (step & 1) * BUFU;
      bool pre = (step + 1 < NSTEP);
      if (pre) stageB(step + 1, (step + 1) & 1);
#pragma unroll
      for (int ks = 0; ks < 2; ++ks) {
        bf16x8 af[4], bfv[4];
#pragma unroll
        for (int mf = 0; mf < 4; ++mf) {
          int Y = mf * 16 + lrow;
          int xs = Y + kx;
          int slot = (wm + ky) * 66 + xs;
          int ko = ((ks * 64 + lk * 16) ^ ((xs & 7) << 4)) >> 1;
          af[mf] = *reinterpret_cast<const bf16x8*>(Araw + slot * 64 + ko);
        }
#pragma unroll
        for (int nf = 0; nf < 4; ++nf) {
          int oc_l = wn * 64 + nf * 16 + lrow;
          int ko = ((ks * 64 + lk * 16) ^ ((oc_l & 7) << 4)) >> 1;
          bfv[nf] = *reinterpret_cast<const bf16x8*>(bcur + oc_l * 64 + ko);
        }
        __builtin_amdgcn_s_setprio(1);
#pragma unroll
        for (int mf = 0; mf < 4; ++mf)
#pragma unroll
          for (int nf = 0; nf < 4; ++nf)
            acc[mf][nf] = __builtin_amdgcn_mfma_f32_16x16x32_bf16(
                af[mf], bfv[nf], acc[mf][nf], 0, 0, 0);
        __builtin_amdgcn_s_setprio(0);
      }
      if (t == 8 && cb + 1 < C1B) {
        S_BARRIER;          // all waves done reading Araw
        stageA(cb + 1);
        WAITV0;             // drains A + the pending B prefetch
        S_BARRIER;
      } else {
        WAITV0;             // B(step+1) landed (flew under the MFMA phase)
        S_BARRIER;
      }
    }
  }

  // ------------------------------ epilogue ----------------------------------
  if constexpr (MODE == 0) {
#pragma unroll
    for (int nf = 0; nf < 4; ++nf) {
      int oc = ocB + wn * 64 + nf * 16 + lrow;
      float bv = bias[oc];
#pragma unroll
      for (int mf = 0; mf < 4; ++mf) {
        int m0 = wm * 64 + mf * 16 + lk * 4;
#pragma unroll
        for (int r = 0; r < 4; ++r) {
          float vv = fmaxf(acc[mf][nf][r] + bv, 0.f);
          int px = P0 + m0 + r;
          int bb = px >> 12, X = (px >> 6) & 63, Y = px & 63;
          outp[((size_t)(bb * 66 + X + 1) * 66 + Y + 1) * NOC + oc] = f2bf(vv);
        }
      }
    }
  } else {
    // wave tile 64x64: X = x0 + wm (single X-col per wave), Y = mf*16+lk*4+r
    int X = x0 + wm;
#pragma unroll
    for (int nf = 0; nf < 4; ++nf) {
      int oc = ocB + wn * 64 + nf * 16 + lrow;
      float bv = bias[oc];
      float s = 0.f;
#pragma unroll
      for (int mf = 0; mf < 4; ++mf) {
#pragma unroll
        for (int r = 0; r < 4; ++r) {
          float vv = fmaxf(acc[mf][nf][r] + bv, 0.f);
          s += vv;
          int Y = mf * 16 + lk * 4 + r;
          if (Y == 0)
            h0raw[((size_t)(b * 64 + X)) * 1024 + oc] = vv;
          else if (Y == 63)
            h63raw[((size_t)(b * 64 + X)) * 1024 + oc] = vv;
        }
      }
      s += __shfl_xor(s, 16);
      s += __shfl_xor(s, 32);
      if (lk == 0)
        U[((size_t)(b * 64 + X)) * 1024 + oc] = s;
    }
  }
}

// ============= fused tail (256 blocks, soft grid barriers) ==================
// Phase A (blk = a*64+xx): T = U@w3^T + 64*b3 ; rows 0/63 @w3^T + b3 ; pooled
// Phase B (blk = a*64+cgi*4+og): dw -> xd -> out values in registers + stats
// Phase C: BN applied from registers, out written once.
__global__ __launch_bounds__(256) void tail_all(
    const float* __restrict__ U, const float* __restrict__ h0raw,
    const float* __restrict__ h63raw, const float* __restrict__ w3,
    const float* __restrict__ b3, const float* __restrict__ wd,
    const float* __restrict__ bd, const float* __restrict__ w4,
    const float* __restrict__ b4, const float* __restrict__ gamma,
    const float* __restrict__ beta, float* __restrict__ T,
    float* __restrict__ h0, float* __restrict__ h63,
    float* __restrict__ pooled, float* __restrict__ stats,
    unsigned* __restrict__ cnts, float* __restrict__ out) {
  int blk = blockIdx.x;
  int tid = threadIdx.x;
  __shared__ float Ul[1024], R0[1024], R63[1024];
  __shared__ float dwl[4][4][9];
  __shared__ float redS[4][16], redQ[4][16];
  __shared__ float mrs[2][64];

  // ------------------------------ phase A -----------------------------------
  {
    int a = blk >> 6, xx = blk & 63;
    const float* ub = U + (size_t)blk * 1024;
    const float* r0b = h0raw + (size_t)blk * 1024;
    const float* r6b = h63raw + (size_t)blk * 1024;
    *reinterpret_cast<float4*>(&Ul[tid * 4]) =
        *reinterpret_cast<const float4*>(&ub[tid * 4]);
    *reinterpret_cast<float4*>(&R0[tid * 4]) =
        *reinterpret_cast<const float4*>(&r0b[tid * 4]);
    *reinterpret_cast<float4*>(&R63[tid * 4]) =
        *reinterpret_cast<const float4*>(&r6b[tid * 4]);
    __syncthreads();
    int c = tid >> 2, g = tid & 3;
    const float* w3r = w3 + c * 1024 + g * 256;
    float sT = 0.f, s0 = 0.f, s6 = 0.f;
    for (int k = 0; k < 256; k += 4) {
      float4 w = *reinterpret_cast<const float4*>(w3r + k);
      int kk = g * 256 + k;
      float4 uu = *reinterpret_cast<const float4*>(&Ul[kk]);
      float4 a0 = *reinterpret_cast<const float4*>(&R0[kk]);
      float4 a6 = *reinterpret_cast<const float4*>(&R63[kk]);
      sT = fmaf(uu.x, w.x, sT); sT = fmaf(uu.y, w.y, sT);
      sT = fmaf(uu.z, w.z, sT); sT = fmaf(uu.w, w.w, sT);
      s0 = fmaf(a0.x, w.x, s0); s0 = fmaf(a0.y, w.y, s0);
      s0 = fmaf(a0.z, w.z, s0); s0 = fmaf(a0.w, w.w, s0);
      s6 = fmaf(a6.x, w.x, s6); s6 = fmaf(a6.y, w.y, s6);
      s6 = fmaf(a6.z, w.z, s6); s6 = fmaf(a6.w, w.w, s6);
    }
    sT += __shfl_xor(sT, 1); sT += __shfl_xor(sT, 2);
    s0 += __shfl_xor(s0, 1); s0 += __shfl_xor(s0, 2);
    s6 += __shfl_xor(s6, 1); s6 += __shfl_xor(s6, 2);
    if (g == 0) {
      float bv = b3[c];
      float tf = sT + 64.f * bv;
      T[(a * 64 + c) * 64 + xx] = tf;
      h0[(a * 64 + c) * 64 + xx] = s0 + bv;
      h63[(a * 64 + c) * 64 + xx] = s6 + bv;
      atomicAdd(&pooled[a * 64 + c], tf * (1.f / 4096.f));
    }
  }
  grid_bar(&cnts[0], tid);

  // ------------------------------ phase B -----------------------------------
  int a = blk >> 6, cgi = (blk >> 2) & 15, og = blk & 3;
  if (tid < 144) {
    int bb = tid / 36, rem = tid % 36, cj = rem / 9, p = rem % 9;
    int r = (cgi * 4 + cj) * 9 + p;
    float s = bd[r];
    const float* pr = pooled + bb * 64;
    const float* wr = wd + r * 64;
    for (int cc = 0; cc < 64; ++cc) s = fmaf(pr[cc], wr[cc], s);
    dwl[bb][cj][p] = s;
  }
  __syncthreads();
  int c4 = tid >> 6, xx = tid & 63;
  int lane = tid & 63, wv = tid >> 6;
  int c = cgi * 4 + c4;
  const float* Tp = T + (a * 64 + c) * 64;
  const float* H0 = h0 + (a * 64 + c) * 64;
  const float* H63 = h63 + (a * 64 + c) * 64;
  float xd4[4] = {0.f, 0.f, 0.f, 0.f};
#pragma unroll
  for (int j = 0; j < 3; ++j) {
    int xi = xx + j - 1;
    if (xi >= 0 && xi < 64) {
      float tv = Tp[xi];
      float S0 = tv - H63[xi];
      float S2 = tv - H0[xi];
#pragma unroll
      for (int bb = 0; bb < 4; ++bb) {
        xd4[bb] = fmaf(dwl[bb][c4][j], S0, xd4[bb]);
        xd4[bb] = fmaf(dwl[bb][c4][3 + j], tv, xd4[bb]);
        xd4[bb] = fmaf(dwl[bb][c4][6 + j], S2, xd4[bb]);
      }
    }
  }
  float vout[16];
#pragma unroll
  for (int oi = 0; oi < 16; ++oi) {
    int o = og * 16 + oi;
    float v = b4[o];
#pragma unroll
    for (int bb = 0; bb < 4; ++bb) v = fmaf(w4[o * 4 + bb], xd4[bb], v);
    vout[oi] = v;
    float sv = v, sq = v * v;
#pragma unroll
    for (int off = 32; off > 0; off >>= 1) {
      sv += __shfl_down(sv, off);
      sq += __shfl_down(sq, off);
    }
    if (lane == 0) { redS[wv][oi] = sv; redQ[wv][oi] = sq; }
  }
  __syncthreads();
  if (tid < 16) {
    float S = redS[0][tid] + redS[1][tid] + redS[2][tid] + redS[3][tid];
    float Q = redQ[0][tid] + redQ[1][tid] + redQ[2][tid] + redQ[3][tid];
    atomicAdd(&stats[og * 16 + tid], S);
    atomicAdd(&stats[64 + og * 16 + tid], Q);
  }
  grid_bar(&cnts[1], tid);

  // ------------------------------ phase C -----------------------------------
  if (tid < 64) {
    float mean = stats[tid] * (1.f / 16384.f);
    float var = stats[64 + tid] * (1.f / 16384.f) - mean * mean;
    mrs[0][tid] = mean;
    mrs[1][tid] = rsqrtf(var + 1e-5f);
  }
  __syncthreads();
  float* op = out + (size_t)a * 262144 + c * 64 + xx;
#pragma unroll
  for (int oi = 0; oi < 16; ++oi) {
    int o = og * 16 + oi;
    op[(size_t)o * 4096] =
        (vout[oi] - mrs[0][o]) * mrs[1][o] * gamma[o] + beta[o];
  }
}

// ---------------------------------------------------------------------------
extern "C" void kernel_launch(void* const* d_in, const int* in_sizes, int n_in,
                              void* d_out, int out_size, void* d_ws,
                              size_t ws_size, hipStream_t stream) {
  const float* x     = (const float*)d_in[0];
  const float* w1    = (const float*)d_in[1];
  const float* b1    = (const float*)d_in[2];
  const float* w2    = (const float*)d_in[3];
  const float* b2    = (const float*)d_in[4];
  const float* w3    = (const float*)d_in[5];
  const float* b3    = (const float*)d_in[6];
  const float* wd    = (const float*)d_in[7];
  const float* bd    = (const float*)d_in[8];
  const float* w4    = (const float*)d_in[9];
  const float* b4    = (const float*)d_in[10];
  const float* gamma = (const float*)d_in[11];
  const float* beta  = (const float*)d_in[12];
  float* out = (float*)d_out;

  // workspace carve (ushort region, then float region). No h2 tensor.
  ushort* us = (ushort*)d_ws;
  ushort* h1n_pad = us;                       // 4,460,544
  ushort* xn_pad  = us + 4460544;             // 1,115,136
  ushort* w1p     = us + 5575680;             // 147,456
  ushort* w2p     = us + 5723136;             // 2,359,296 -> ends 8,082,432
  float* fbase    = (float*)(us + 8082432);
  float* Ub      = fbase;                     // 262,144
  float* pooled  = Ub + 262144;               // 256  (zeroed each call)
  float* stats   = pooled + 256;              // 128  (zeroed each call)
  unsigned* cnts = (unsigned*)(stats + 128);  // 32   (zeroed each call)
  float* Tb      = stats + 160;               // 16,384
  float* h0b     = Tb + 16384;                // 16,384
  float* h63b    = h0b + 16384;               // 16,384
  float* h0raw   = h63b + 16384;              // 262,144
  float* h63raw  = h0raw + 262144;            // 262,144

  pack_all<<<2393, 256, 0, stream>>>(x, w1, w2, xn_pad, w1p, w2p, h1n_pad,
                                     pooled);

  // LDS = 33792 (A) + 2*16384 (B dbuf) = 66560 -> 2 blocks/CU
  hipFuncSetAttribute(
      reinterpret_cast<const void*>(conv_gemm3<1, 256, 0>),
      hipFuncAttributeMaxDynamicSharedMemorySize, 66560);
  hipFuncSetAttribute(
      reinterpret_cast<const void*>(conv_gemm3<4, 1024, 1>),
      hipFuncAttributeMaxDynamicSharedMemorySize, 66560);

  conv_gemm3<1, 256, 0>
      <<<dim3(128, 2), 256, 66560, stream>>>(xn_pad, w1p, b1, h1n_pad,
                                             nullptr, nullptr, nullptr);
  conv_gemm3<4, 1024, 1>
      <<<dim3(128, 8), 256, 66560, stream>>>(h1n_pad, w2p, b2, nullptr,
                                             Ub, h0raw, h63raw);

  tail_all<<<256, 256, 0, stream>>>(Ub, h0raw, h63raw, w3, b3, wd, bd, w4,
                                    b4, gamma, beta, Tb, h0b, h63b, pooled,
                                    stats, cnts, out);
}

// Round 16
// 113.323 us; speedup vs baseline: 1.7254x; 1.7254x over previous
//
#include <hip/hip_runtime.h>
#include <hip/hip_bf16.h>
#include <math.h>

typedef unsigned short ushort;
typedef __attribute__((ext_vector_type(8))) short bf16x8;
typedef __attribute__((ext_vector_type(4))) float f32x4;
typedef __attribute__((ext_vector_type(8))) ushort ushort8;

__device__ inline ushort f2bf(float f) {
  __hip_bfloat16 h = __float2bfloat16(f);
  return *reinterpret_cast<ushort*>(&h);
}

typedef __attribute__((address_space(3))) unsigned int lds_u32;
typedef __attribute__((address_space(1))) const unsigned int glb_u32;
__device__ __forceinline__ void gl2lds16(const ushort* g, ushort* l) {
  __builtin_amdgcn_global_load_lds((glb_u32*)g, (lds_u32*)l, 16, 0, 0);
}

#define S_BARRIER asm volatile("s_barrier" ::: "memory")
#define WAITV0 asm volatile("s_waitcnt vmcnt(0)" ::: "memory")

// ============================ pack_all =====================================
// X-MAJOR world: spatial transpose. xn_pad[b][66 Xp][66 Yp][64 c].
// Weights tap-transposed: wp[t'] = w_orig[ky = t'%3][kx = t'/3].
__global__ __launch_bounds__(256) void pack_all(
    const float* __restrict__ x, const float* __restrict__ w1,
    const float* __restrict__ w2, ushort* __restrict__ xn_pad,
    ushort* __restrict__ w1p, ushort* __restrict__ w2p,
    ushort* __restrict__ h1n_pad, float* __restrict__ zbase) {
  int blk = blockIdx.x;
  int tid = threadIdx.x;
  __shared__ float ld[64][65];
  if (blk < 264) {
    int b = blk / 66, yp = blk % 66;
    if (yp == 0 || yp == 65) {
      for (int i = tid; i < 66 * 64; i += 256) {
        int xp = i >> 6, c = i & 63;
        xn_pad[((size_t)(b * 66 + xp)) * 4224 + yp * 64 + c] = 0;
      }
      return;
    }
    int y = yp - 1;
    int xx = tid & 63;
#pragma unroll
    for (int i = 0; i < 16; ++i) {
      int c = i * 4 + (tid >> 6);
      ld[c][xx] = x[((b * 64 + c) * 64 + y) * 64 + xx];
    }
    __syncthreads();
    for (int i = tid; i < 2 * 64; i += 256) {
      int side = i >> 6, c = i & 63;
      xn_pad[((size_t)(b * 66 + (side ? 65 : 0))) * 4224 + yp * 64 + c] = 0;
    }
    for (int u = tid; u < 64 * 8; u += 256) {
      int xp = u >> 3, cg = u & 7;
      ushort8 v;
#pragma unroll
      for (int j = 0; j < 8; ++j) v[j] = f2bf(ld[cg * 8 + j][xp]);
      *reinterpret_cast<ushort8*>(
          &xn_pad[((size_t)(b * 66 + xp + 1)) * 4224 + yp * 64 + cg * 8]) = v;
    }
  } else if (blk < 328) {
    int idx = (blk - 264) * 256 + tid;  // OC=256, CIN=64
    float v[9];
#pragma unroll
    for (int t = 0; t < 9; ++t) v[t] = w1[idx * 9 + t];
    int oc = idx >> 6, c = idx & 63;
#pragma unroll
    for (int tp = 0; tp < 9; ++tp)
      w1p[(tp * 256 + oc) * 64 + c] = f2bf(v[(tp % 3) * 3 + tp / 3]);
  } else if (blk < 1352) {
    int idx = (blk - 328) * 256 + tid;  // OC=1024, CIN=256
    float v[9];
#pragma unroll
    for (int t = 0; t < 9; ++t) v[t] = w2[(size_t)idx * 9 + t];
    int oc = idx >> 8, c = idx & 255;
#pragma unroll
    for (int tp = 0; tp < 9; ++tp)
      w2p[((size_t)tp * 1024 + oc) * 256 + c] = f2bf(v[(tp % 3) * 3 + tp / 3]);
  } else if (blk < 2392) {
    int k = blk - 1352;  // 0..1039
    int b = k / 260, p = k % 260;
    int yp, xp;
    if (p < 66) { yp = 0; xp = p; }
    else if (p < 132) { yp = 65; xp = p - 66; }
    else if (p < 196) { yp = p - 132 + 1; xp = 0; }
    else { yp = p - 196 + 1; xp = 65; }
    h1n_pad[((size_t)(b * 66 + xp) * 66 + yp) * 256 + tid] = 0;
  } else {
    if (tid < 96) {
      float4 z = {0.f, 0.f, 0.f, 0.f};
      *reinterpret_cast<float4*>(zbase + tid * 4) = z;
    }
  }
}

// ========== 2-block/CU pipelined implicit-GEMM conv (3x3, pad 1) ============
// R8-proven structure (77.7us, MfmaUtil 41%, 0 bank conflicts), 16x16x32 MFMA.
// Six schedule variants (lockstep / phase-split / 2-block overlap / 32x32
// shape / desync / stagger) all converge to 78+-6us -> structural floor for
// this loop (mixed LDS-read-throughput + VALU bound).
// X-major. in_pad: [b][66 X][66 Y][CIN] bf16. wpack: [9][NOC][CIN].
// BM=128 (2 X-cols x 64 Y), BN=128, 4 waves (2M x 2N), wave tile 64x64.
// LDS = A 33792 + 2 x 16384 B = 66560 -> 2 blocks/CU.
template<int C1B, int NOC, int MODE>
__global__ __launch_bounds__(256, 2) void conv_gemm3(
    const ushort* __restrict__ in_pad, const ushort* __restrict__ wpack,
    const float* __restrict__ bias, ushort* __restrict__ outp,
    float* __restrict__ U, float* __restrict__ h0raw,
    float* __restrict__ h63raw) {
  constexpr int CIN = C1B * 64;
  constexpr int NSTEP = C1B * 9;
  constexpr int BN = 128;
  constexpr int BUFU = BN * 64;      // 8192 ushorts per B buffer
  constexpr int ACH = 4 * 66 * 8;    // 2112 A chunks (4 X-rows x 66 Y x 8)
  extern __shared__ ushort lds[];
  ushort* Araw = lds;                // 33792 B
  ushort* Bb = lds + ACH * 8;        // 2 x 16384 B
  int tid = threadIdx.x;
  int wid = tid >> 6, lane = tid & 63;
  int lrow = lane & 15, lk = lane >> 4;
  int wm = wid >> 1, wn = wid & 1;
  int bx = blockIdx.x, by = blockIdx.y;
  if constexpr (MODE == 1) {         // XCD swizzle: each XCD owns one B panel
    int id = bx + 128 * by;          // grid (128, 8), 1024 blocks
    int swz = (id & 7) * 128 + (id >> 3);
    bx = swz & 127;
    by = swz >> 7;
  }
  int P0 = bx * 128;
  int b = P0 >> 12;
  int x0 = (P0 & 4095) >> 6;         // X-pair origin
  int ocB = by * BN;
  f32x4 acc[4][4] = {};

  // precomputed per-thread staging offsets
  int aoff[9];
#pragma unroll
  for (int it = 0; it < 9; ++it) {
    int ch = it * 256 + tid;
    int slot = ch >> 3, cg = ch & 7;
    int xs = slot % 66;
    int cgp = cg ^ (xs & 7);
    aoff[it] = slot * CIN + cgp * 8;
  }
  int boff[4];
#pragma unroll
  for (int it = 0; it < 4; ++it) {
    int ch = it * 256 + tid;
    int oc = ch >> 3, cg = ch & 7;
    int cgp = cg ^ (oc & 7);
    boff[it] = oc * CIN + cgp * 8;
  }

  auto stageA = [&](int cb) {
    const ushort* asrc = in_pad + (size_t)(b * 66 + x0) * 66 * CIN + cb * 64;
#pragma unroll
    for (int it = 0; it < 9; ++it) {
      int basech = it * 256 + wid * 64;
      if (basech < ACH)
        gl2lds16(asrc + aoff[it], Araw + basech * 8);
    }
  };
  auto stageB = [&](int sstep, int q) {
    const ushort* wsrc =
        wpack + ((size_t)(sstep % 9) * NOC + ocB) * CIN + (sstep / 9) * 64;
    ushort* dbase = Bb + q * BUFU;
#pragma unroll
    for (int it = 0; it < 4; ++it)
      gl2lds16(wsrc + boff[it], dbase + (it * 256 + wid * 64) * 8);
  };

  // prologue
  stageA(0);
  stageB(0, 0);
  WAITV0;
  S_BARRIER;

#pragma unroll 1
  for (int cb = 0; cb < C1B; ++cb) {
#pragma unroll 1
    for (int t = 0; t < 9; ++t) {
      int step = cb * 9 + t;
      int ky = t / 3, kx = t - ky * 3;
      const ushort* bcur = Bb + (step & 1) * BUFU;
      bool pre = (step + 1 < NSTEP);
      if (pre) stageB(step + 1, (step + 1) & 1);
#pragma unroll
      for (int ks = 0; ks < 2; ++ks) {
        bf16x8 af[4], bfv[4];
#pragma unroll
        for (int mf = 0; mf < 4; ++mf) {
          int Y = mf * 16 + lrow;
          int xs = Y + kx;
          int slot = (wm + ky) * 66 + xs;
          int ko = ((ks * 64 + lk * 16) ^ ((xs & 7) << 4)) >> 1;
          af[mf] = *reinterpret_cast<const bf16x8*>(Araw + slot * 64 + ko);
        }
#pragma unroll
        for (int nf = 0; nf < 4; ++nf) {
          int oc_l = wn * 64 + nf * 16 + lrow;
          int ko = ((ks * 64 + lk * 16) ^ ((oc_l & 7) << 4)) >> 1;
          bfv[nf] = *reinterpret_cast<const bf16x8*>(bcur + oc_l * 64 + ko);
        }
        __builtin_amdgcn_s_setprio(1);
#pragma unroll
        for (int mf = 0; mf < 4; ++mf)
#pragma unroll
          for (int nf = 0; nf < 4; ++nf)
            acc[mf][nf] = __builtin_amdgcn_mfma_f32_16x16x32_bf16(
                af[mf], bfv[nf], acc[mf][nf], 0, 0, 0);
        __builtin_amdgcn_s_setprio(0);
      }
      if (t == 8 && cb + 1 < C1B) {
        S_BARRIER;          // all waves done reading Araw
        stageA(cb + 1);
        WAITV0;             // drains A + the pending B prefetch
        S_BARRIER;
      } else {
        WAITV0;             // B(step+1) landed (flew under the MFMA phase)
        S_BARRIER;
      }
    }
  }

  // ------------------------------ epilogue ----------------------------------
  if constexpr (MODE == 0) {
#pragma unroll
    for (int nf = 0; nf < 4; ++nf) {
      int oc = ocB + wn * 64 + nf * 16 + lrow;
      float bv = bias[oc];
#pragma unroll
      for (int mf = 0; mf < 4; ++mf) {
        int m0 = wm * 64 + mf * 16 + lk * 4;
#pragma unroll
        for (int r = 0; r < 4; ++r) {
          float vv = fmaxf(acc[mf][nf][r] + bv, 0.f);
          int px = P0 + m0 + r;
          int bb = px >> 12, X = (px >> 6) & 63, Y = px & 63;
          outp[((size_t)(bb * 66 + X + 1) * 66 + Y + 1) * NOC + oc] = f2bf(vv);
        }
      }
    }
  } else {
    // wave tile 64x64: X = x0 + wm (single X-col per wave), Y = mf*16+lk*4+r
    int X = x0 + wm;
#pragma unroll
    for (int nf = 0; nf < 4; ++nf) {
      int oc = ocB + wn * 64 + nf * 16 + lrow;
      float bv = bias[oc];
      float s = 0.f;
#pragma unroll
      for (int mf = 0; mf < 4; ++mf) {
#pragma unroll
        for (int r = 0; r < 4; ++r) {
          float vv = fmaxf(acc[mf][nf][r] + bv, 0.f);
          s += vv;
          int Y = mf * 16 + lk * 4 + r;
          if (Y == 0)
            h0raw[((size_t)(b * 64 + X)) * 1024 + oc] = vv;
          else if (Y == 63)
            h63raw[((size_t)(b * 64 + X)) * 1024 + oc] = vv;
        }
      }
      s += __shfl_xor(s, 16);
      s += __shfl_xor(s, 32);
      if (lk == 0)
        U[((size_t)(b * 64 + X)) * 1024 + oc] = s;
    }
  }
}

// ---- tailB: per (a,x): T = U@w3^T + 64*b3 ; rows 0/63 @w3^T + b3 ; pooled --
__global__ __launch_bounds__(256) void tailB(
    const float* __restrict__ U, const float* __restrict__ h0raw,
    const float* __restrict__ h63raw, const float* __restrict__ w3,
    const float* __restrict__ b3, float* __restrict__ T,
    float* __restrict__ h0, float* __restrict__ h63,
    float* __restrict__ pooled) {
  int blk = blockIdx.x;  // a*64 + xx
  int a = blk >> 6, xx = blk & 63;
  __shared__ float Ul[1024], R0[1024], R63[1024];
  int tid = threadIdx.x;
  const float* ub = U + (size_t)blk * 1024;
  const float* r0b = h0raw + (size_t)blk * 1024;
  const float* r6b = h63raw + (size_t)blk * 1024;
  *reinterpret_cast<float4*>(&Ul[tid * 4]) =
      *reinterpret_cast<const float4*>(&ub[tid * 4]);
  *reinterpret_cast<float4*>(&R0[tid * 4]) =
      *reinterpret_cast<const float4*>(&r0b[tid * 4]);
  *reinterpret_cast<float4*>(&R63[tid * 4]) =
      *reinterpret_cast<const float4*>(&r6b[tid * 4]);
  __syncthreads();
  int c = tid >> 2, g = tid & 3;
  const float* w3r = w3 + c * 1024 + g * 256;
  float sT = 0.f, s0 = 0.f, s6 = 0.f;
  for (int k = 0; k < 256; k += 4) {
    float4 w = *reinterpret_cast<const float4*>(w3r + k);
    int kk = g * 256 + k;
    float4 uu = *reinterpret_cast<const float4*>(&Ul[kk]);
    float4 a0 = *reinterpret_cast<const float4*>(&R0[kk]);
    float4 a6 = *reinterpret_cast<const float4*>(&R63[kk]);
    sT = fmaf(uu.x, w.x, sT); sT = fmaf(uu.y, w.y, sT);
    sT = fmaf(uu.z, w.z, sT); sT = fmaf(uu.w, w.w, sT);
    s0 = fmaf(a0.x, w.x, s0); s0 = fmaf(a0.y, w.y, s0);
    s0 = fmaf(a0.z, w.z, s0); s0 = fmaf(a0.w, w.w, s0);
    s6 = fmaf(a6.x, w.x, s6); s6 = fmaf(a6.y, w.y, s6);
    s6 = fmaf(a6.z, w.z, s6); s6 = fmaf(a6.w, w.w, s6);
  }
  sT += __shfl_xor(sT, 1); sT += __shfl_xor(sT, 2);
  s0 += __shfl_xor(s0, 1); s0 += __shfl_xor(s0, 2);
  s6 += __shfl_xor(s6, 1); s6 += __shfl_xor(s6, 2);
  if (g == 0) {
    float bv = b3[c];
    float tf = sT + 64.f * bv;
    T[(a * 64 + c) * 64 + xx] = tf;
    h0[(a * 64 + c) * 64 + xx] = s0 + bv;
    h63[(a * 64 + c) * 64 + xx] = s6 + bv;
    atomicAdd(&pooled[a * 64 + c], tf * (1.f / 4096.f));
  }
}

// ---- xdout256: dw -> xd (reg) -> out (pre-BN) + stats; 256 blocks ----------
// blk = a*64 + cgi*4 + og ; thread = c4*64 + xx ; each thread: 16 o-outputs.
__global__ __launch_bounds__(256) void xdout256(
    const float* __restrict__ T, const float* __restrict__ h0,
    const float* __restrict__ h63, const float* __restrict__ pooled,
    const float* __restrict__ wd, const float* __restrict__ bd,
    const float* __restrict__ w4, const float* __restrict__ b4,
    float* __restrict__ out, float* __restrict__ stats) {
  int blk = blockIdx.x;
  int a = blk >> 6, cgi = (blk >> 2) & 15, og = blk & 3;
  int t = threadIdx.x;
  __shared__ float dwl[4][4][9];
  __shared__ float redS[4][16], redQ[4][16];
  if (t < 144) {
    int bb = t / 36, rem = t % 36, cj = rem / 9, p = rem % 9;
    int r = (cgi * 4 + cj) * 9 + p;
    float s = bd[r];
    const float* pr = pooled + bb * 64;
    const float* wr = wd + r * 64;
    for (int cc = 0; cc < 64; ++cc) s = fmaf(pr[cc], wr[cc], s);
    dwl[bb][cj][p] = s;
  }
  __syncthreads();
  int c4 = t >> 6, xx = t & 63;
  int lane = t & 63, wv = t >> 6;
  int c = cgi * 4 + c4;
  const float* Tp = T + (a * 64 + c) * 64;
  const float* H0 = h0 + (a * 64 + c) * 64;
  const float* H63 = h63 + (a * 64 + c) * 64;
  float xd4[4] = {0.f, 0.f, 0.f, 0.f};
#pragma unroll
  for (int j = 0; j < 3; ++j) {
    int xi = xx + j - 1;
    if (xi >= 0 && xi < 64) {
      float tv = Tp[xi];
      float S0 = tv - H63[xi];
      float S2 = tv - H0[xi];
#pragma unroll
      for (int bb = 0; bb < 4; ++bb) {
        xd4[bb] = fmaf(dwl[bb][c4][j], S0, xd4[bb]);
        xd4[bb] = fmaf(dwl[bb][c4][3 + j], tv, xd4[bb]);
        xd4[bb] = fmaf(dwl[bb][c4][6 + j], S2, xd4[bb]);
      }
    }
  }
  float* op = out + (size_t)a * 262144 + c * 64 + xx;
#pragma unroll
  for (int oi = 0; oi < 16; ++oi) {
    int o = og * 16 + oi;
    float v = b4[o];
#pragma unroll
    for (int bb = 0; bb < 4; ++bb) v = fmaf(w4[o * 4 + bb], xd4[bb], v);
    op[(size_t)o * 4096] = v;
    float sv = v, sq = v * v;
#pragma unroll
    for (int off = 32; off > 0; off >>= 1) {
      sv += __shfl_down(sv, off);
      sq += __shfl_down(sq, off);
    }
    if (lane == 0) { redS[wv][oi] = sv; redQ[wv][oi] = sq; }
  }
  __syncthreads();
  if (t < 16) {
    float S = redS[0][t] + redS[1][t] + redS[2][t] + redS[3][t];
    float Q = redQ[0][t] + redQ[1][t] + redQ[2][t] + redQ[3][t];
    atomicAdd(&stats[og * 16 + t], S);
    atomicAdd(&stats[64 + og * 16 + t], Q);
  }
}

// ------------------- batchnorm apply (stats from xdout) ---------------------
__global__ __launch_bounds__(256) void bnapply_kernel(
    float* __restrict__ out, const float* __restrict__ stats,
    const float* __restrict__ gamma, const float* __restrict__ beta) {
  int idx = blockIdx.x * 256 + threadIdx.x;
  int o = (idx >> 12) & 63;
  float mean = stats[o] * (1.f / 16384.f);
  float var = stats[64 + o] * (1.f / 16384.f) - mean * mean;
  float rstd = rsqrtf(var + 1e-5f);
  out[idx] = (out[idx] - mean) * rstd * gamma[o] + beta[o];
}

// ---------------------------------------------------------------------------
extern "C" void kernel_launch(void* const* d_in, const int* in_sizes, int n_in,
                              void* d_out, int out_size, void* d_ws,
                              size_t ws_size, hipStream_t stream) {
  const float* x     = (const float*)d_in[0];
  const float* w1    = (const float*)d_in[1];
  const float* b1    = (const float*)d_in[2];
  const float* w2    = (const float*)d_in[3];
  const float* b2    = (const float*)d_in[4];
  const float* w3    = (const float*)d_in[5];
  const float* b3    = (const float*)d_in[6];
  const float* wd    = (const float*)d_in[7];
  const float* bd    = (const float*)d_in[8];
  const float* w4    = (const float*)d_in[9];
  const float* b4    = (const float*)d_in[10];
  const float* gamma = (const float*)d_in[11];
  const float* beta  = (const float*)d_in[12];
  float* out = (float*)d_out;

  // workspace carve (ushort region, then float region). No h2 tensor.
  ushort* us = (ushort*)d_ws;
  ushort* h1n_pad = us;                       // 4,460,544
  ushort* xn_pad  = us + 4460544;             // 1,115,136
  ushort* w1p     = us + 5575680;             // 147,456
  ushort* w2p     = us + 5723136;             // 2,359,296 -> ends 8,082,432
  float* fbase    = (float*)(us + 8082432);
  float* Ub      = fbase;                     // 262,144
  float* pooled  = Ub + 262144;               // 256  (zeroed each call)
  float* stats   = pooled + 256;              // 128  (zeroed each call)
  float* Tb      = stats + 128;               // 16,384
  float* h0b     = Tb + 16384;                // 16,384
  float* h63b    = h0b + 16384;               // 16,384
  float* h0raw   = h63b + 16384;              // 262,144
  float* h63raw  = h0raw + 262144;            // 262,144

  pack_all<<<2393, 256, 0, stream>>>(x, w1, w2, xn_pad, w1p, w2p, h1n_pad,
                                     pooled);

  // LDS = 33792 (A) + 2*16384 (B dbuf) = 66560 -> 2 blocks/CU
  hipFuncSetAttribute(
      reinterpret_cast<const void*>(conv_gemm3<1, 256, 0>),
      hipFuncAttributeMaxDynamicSharedMemorySize, 66560);
  hipFuncSetAttribute(
      reinterpret_cast<const void*>(conv_gemm3<4, 1024, 1>),
      hipFuncAttributeMaxDynamicSharedMemorySize, 66560);

  conv_gemm3<1, 256, 0>
      <<<dim3(128, 2), 256, 66560, stream>>>(xn_pad, w1p, b1, h1n_pad,
                                             nullptr, nullptr, nullptr);
  conv_gemm3<4, 1024, 1>
      <<<dim3(128, 8), 256, 66560, stream>>>(h1n_pad, w2p, b2, nullptr,
                                             Ub, h0raw, h63raw);

  tailB<<<256, 256, 0, stream>>>(Ub, h0raw, h63raw, w3, b3, Tb, h0b, h63b,
                                 pooled);
  xdout256<<<256, 256, 0, stream>>>(Tb, h0b, h63b, pooled, wd, bd, w4, b4,
                                    out, stats);
  bnapply_kernel<<<4096, 256, 0, stream>>>(out, stats, gamma, beta);
}